// Round 1
// baseline (1145.169 us; speedup 1.0000x reference)
//
#include <hip/hip_runtime.h>
#include <math.h>

typedef unsigned short u16;
typedef unsigned int u32;

typedef __attribute__((ext_vector_type(8))) short short8;
typedef __attribute__((ext_vector_type(4))) float floatx4;
typedef __attribute__((ext_vector_type(4))) unsigned short ushort4v;

#define DD 1024
#define HH 16
#define HD 64
#define SS 1024
#define BBATCH 8
#define FFDIM 4096
#define MM (BBATCH*SS)   // 8192 rows

__device__ __forceinline__ float bf2f(u16 v){ u32 x = ((u32)v)<<16; return __builtin_bit_cast(float, x); }
__device__ __forceinline__ u16 f2bf(float f){
  u32 x = __builtin_bit_cast(u32, f);
  u32 r = (x + 0x7fffu + ((x>>16)&1u)) >> 16;
  return (u16)r;
}

__device__ __forceinline__ void gload_lds16(const void* g, void* l){
  __builtin_amdgcn_global_load_lds((const __attribute__((address_space(1))) void*)g,
                                   (__attribute__((address_space(3))) void*)l, 16, 0, 0);
}

// ---------------------------------------------------------------------------
// Weight transpose + fp32->bf16 cast: W[K][N] -> Wt[N][K]
// ---------------------------------------------------------------------------
__global__ __launch_bounds__(256) void wtrans_k(const float* __restrict__ W,
                                                u16* __restrict__ Wt, int K, int N)
{
  __shared__ u16 tile[64][68];
  const int nt = blockIdx.x*64, kt = blockIdx.y*64;
  const int t = threadIdx.x;
  const int kl = t>>4, nl4 = (t&15)*4;
  #pragma unroll
  for (int r=0;r<4;r++){
    float4 v = *(const float4*)(W + (size_t)(kt + r*16 + kl)*N + nt + nl4);
    ushort4v u; u.x=f2bf(v.x); u.y=f2bf(v.y); u.z=f2bf(v.z); u.w=f2bf(v.w);
    *(ushort4v*)(&tile[r*16+kl][nl4]) = u;
  }
  __syncthreads();
  #pragma unroll
  for (int r=0;r<16;r++){
    int idx = r*256 + t;
    int nl = idx>>6, klc = idx&63;
    Wt[(size_t)(nt+nl)*K + kt + klc] = tile[klc][nl];
  }
}

// ---------------------------------------------------------------------------
// fp32 -> bf16 cast (8M elements, grid 2048x256, 4 float4 per thread)
// ---------------------------------------------------------------------------
__global__ __launch_bounds__(256) void cast_k(const float* __restrict__ in, u16* __restrict__ out)
{
  size_t i = (size_t)blockIdx.x*256 + threadIdx.x;
  #pragma unroll
  for (int r=0;r<4;r++){
    size_t idx = i + (size_t)r*524288;
    float4 v = ((const float4*)in)[idx];
    ushort4v u; u.x=f2bf(v.x); u.y=f2bf(v.y); u.z=f2bf(v.z); u.w=f2bf(v.w);
    ((ushort4v*)out)[idx] = u;
  }
}

// ---------------------------------------------------------------------------
// LayerNorm: one block (256 threads) per row of 1024. Input fp32 or bf16.
// ---------------------------------------------------------------------------
template<int IN_BF16>
__global__ __launch_bounds__(256) void ln_k(const void* __restrict__ inv,
    const float* __restrict__ g, const float* __restrict__ bb, u16* __restrict__ out)
{
  const int row = blockIdx.x, t = threadIdx.x;
  float x[4];
  if (IN_BF16){
    const u16* in = (const u16*)inv;
    ushort4v v = ((const ushort4v*)(in + (size_t)row*DD))[t];
    #pragma unroll
    for (int i=0;i<4;i++) x[i]=bf2f(v[i]);
  } else {
    const float* in = (const float*)inv;
    float4 v = ((const float4*)(in + (size_t)row*DD))[t];
    x[0]=v.x; x[1]=v.y; x[2]=v.z; x[3]=v.w;
  }
  float s = x[0]+x[1]+x[2]+x[3];
  float q = x[0]*x[0]+x[1]*x[1]+x[2]*x[2]+x[3]*x[3];
  #pragma unroll
  for (int m=32;m;m>>=1){ s += __shfl_down(s,m); q += __shfl_down(q,m); }
  __shared__ float red[8];
  const int lane=t&63, wid=t>>6;
  if (lane==0){ red[wid]=s; red[wid+4]=q; }
  __syncthreads();
  s = red[0]+red[1]+red[2]+red[3];
  q = red[4]+red[5]+red[6]+red[7];
  const float mu = s*(1.0f/1024.0f);
  const float var = q*(1.0f/1024.0f) - mu*mu;
  const float rs = rsqrtf(var + 1e-5f);
  const int c = t*4;
  ushort4v ov;
  #pragma unroll
  for (int i=0;i<4;i++){
    float y = (x[i]-mu)*rs*g[c+i] + bb[c+i];
    ov[i] = f2bf(y);
  }
  ((ushort4v*)(out + (size_t)row*DD))[t] = ov;
}

// ---------------------------------------------------------------------------
// bf16 GEMM: C[M,N] = A[M,K] @ Wt[N,K]^T + bias.  128x128 tile, BK=32, 4 waves.
// MODE 0: scatter to [B,H,S,HD] bf16    MODE 1: bf16 flat, += res(bf16)
// MODE 2: bf16 flat, exact GELU         MODE 3: fp32 flat, += res(bf16)
// ---------------------------------------------------------------------------
template<int MODE>
__global__ __launch_bounds__(256) void gemm_k(
    const u16* __restrict__ A, const u16* __restrict__ Bt,
    const float* __restrict__ bias, const u16* __restrict__ res,
    void* __restrict__ Cout, int N, int K)
{
  __shared__ u16 smem[8192];            // A tile [128][32] then B tile [128][32]
  u16* sA = smem; u16* sB = smem + 4096;
  const int t = threadIdx.x;
  const int n0 = blockIdx.x*128, m0 = blockIdx.y*128;
  const int lane = t & 63, wid = t >> 6;
  const int wr = wid >> 1, wc = wid & 1;
  const int lrow = lane & 15, lk8 = (lane >> 4) * 8;

  floatx4 acc[4][4];
  #pragma unroll
  for (int i=0;i<4;i++)
    #pragma unroll
    for (int j=0;j<4;j++) acc[i][j] = (floatx4)0.0f;

  const u16* gA = A + (size_t)m0 * K;
  const u16* gB = Bt + (size_t)n0 * K;
  const int c0row = t >> 2, c0col = (t & 3) * 8;
  const int nk = K >> 5;
  for (int kt = 0; kt < nk; ++kt) {
    const u16* gAk = gA + kt*32;
    const u16* gBk = gB + kt*32;
    gload_lds16(gAk + (size_t)c0row * K + c0col,      sA + t*8);
    gload_lds16(gAk + (size_t)(c0row+64) * K + c0col, sA + 2048 + t*8);
    gload_lds16(gBk + (size_t)c0row * K + c0col,      sB + t*8);
    gload_lds16(gBk + (size_t)(c0row+64) * K + c0col, sB + 2048 + t*8);
    __syncthreads();
    short8 a[4], b[4];
    #pragma unroll
    for (int mi=0; mi<4; mi++) a[mi] = *(const short8*)(sA + (wr*64 + mi*16 + lrow)*32 + lk8);
    #pragma unroll
    for (int ni=0; ni<4; ni++) b[ni] = *(const short8*)(sB + (wc*64 + ni*16 + lrow)*32 + lk8);
    #pragma unroll
    for (int mi=0; mi<4; mi++)
      #pragma unroll
      for (int ni=0; ni<4; ni++)
        acc[mi][ni] = __builtin_amdgcn_mfma_f32_16x16x32_bf16(a[mi], b[ni], acc[mi][ni], 0,0,0);
    __syncthreads();
  }

  #pragma unroll
  for (int mi=0; mi<4; mi++) {
    const int row_base = m0 + wr*64 + mi*16 + (lane>>4)*4;
    #pragma unroll
    for (int ni=0; ni<4; ni++) {
      const int col = n0 + wc*64 + ni*16 + lrow;
      const float bv = bias[col];
      floatx4 v = acc[mi][ni];
      #pragma unroll
      for (int r=0;r<4;r++){
        const int row = row_base + r;
        float x = v[r] + bv;
        const size_t f = (size_t)row * N + col;
        if (MODE==0){
          const int b = row >> 10, s = row & 1023;
          const int h = col >> 6, d = col & 63;
          ((u16*)Cout)[ (((size_t)(b*HH+h)*SS + s)<<6) + d ] = f2bf(x);
        } else if (MODE==1){
          ((u16*)Cout)[f] = f2bf(x + bf2f(res[f]));
        } else if (MODE==2){
          float gx = 0.5f * x * (1.0f + erff(x * 0.70710678f));
          ((u16*)Cout)[f] = f2bf(gx);
        } else {
          ((float*)Cout)[f] = x + bf2f(res[f]);
        }
      }
    }
  }
}

// ---------------------------------------------------------------------------
// Flash attention: 4 waves/block, each wave 16 q-rows; K-tiles of 32.
// Q,K,V in [B*H, S, 64] bf16; output rep[b][s][h*64+d] bf16.
// ---------------------------------------------------------------------------
template<int CAUSAL>
__global__ __launch_bounds__(256) void attn_k(
  const u16* __restrict__ Q, const u16* __restrict__ Kk, const u16* __restrict__ V,
  u16* __restrict__ rep)
{
  __shared__ u16 klds[32][72];   // keys x hd   (+8 pad)
  __shared__ u16 vt[64][40];     // hd x keys   (+8 pad)
  __shared__ u16 pl[4][16][40];  // per-wave P  (+8 pad)
  const int t = threadIdx.x, lane = t&63, wid = t>>6;
  const int qb = blockIdx.x & 15;
  const int bh = blockIdx.x >> 4;
  const int q0 = qb*64;
  const int qw = q0 + wid*16;
  const int lrow = lane&15, lk8 = (lane>>4)*8;
  const size_t base = (size_t)bh * SS * HD;

  short8 qf[2];
  {
    const u16* qp = Q + base + (size_t)(qw + lrow)*HD + lk8;
    qf[0] = *(const short8*)(qp);
    qf[1] = *(const short8*)(qp + 32);
  }
  floatx4 o[4];
  #pragma unroll
  for (int co=0;co<4;co++) o[co] = (floatx4)0.0f;
  float mrow[4] = {-INFINITY,-INFINITY,-INFINITY,-INFINITY};
  float lsum[4] = {0.f,0.f,0.f,0.f};

  const int ntiles = CAUSAL ? ((q0+64) >> 5) : (SS>>5);
  for (int kt=0; kt<ntiles; ++kt){
    const int k0 = kt<<5;
    {
      const int row = t>>3, c8 = (t&7)*8;
      short8 kv = *(const short8*)(Kk + base + (size_t)(k0+row)*HD + c8);
      *(short8*)(&klds[row][c8]) = kv;
      short8 vv = *(const short8*)(V + base + (size_t)(k0+row)*HD + c8);
      #pragma unroll
      for (int j=0;j<8;j++) vt[c8+j][row] = (u16)vv[j];
    }
    __syncthreads();

    float pv[2][4];
    #pragma unroll
    for (int c=0;c<2;c++){
      short8 kf0 = *(const short8*)(&klds[c*16 + lrow][lk8]);
      short8 kf1 = *(const short8*)(&klds[c*16 + lrow][32 + lk8]);
      floatx4 z = (floatx4)0.0f;
      z = __builtin_amdgcn_mfma_f32_16x16x32_bf16(qf[0], kf0, z, 0,0,0);
      z = __builtin_amdgcn_mfma_f32_16x16x32_bf16(qf[1], kf1, z, 0,0,0);
      #pragma unroll
      for (int r=0;r<4;r++){
        float s = z[r]*0.125f;
        if (CAUSAL){
          const int key = k0 + c*16 + lrow;
          const int qrow = qw + (lane>>4)*4 + r;
          if (key > qrow) s = -INFINITY;
        }
        pv[c][r] = s;
      }
    }
    float tm[4];
    #pragma unroll
    for (int r=0;r<4;r++) tm[r] = fmaxf(pv[0][r], pv[1][r]);
    #pragma unroll
    for (int m=1;m<16;m<<=1){
      #pragma unroll
      for (int r=0;r<4;r++) tm[r] = fmaxf(tm[r], __shfl_xor(tm[r], m));
    }
    float al[4];
    #pragma unroll
    for (int r=0;r<4;r++){
      float mn = fmaxf(mrow[r], tm[r]);
      al[r] = __expf(mrow[r]-mn);
      mrow[r] = mn;
    }
    float ts[4] = {0.f,0.f,0.f,0.f};
    #pragma unroll
    for (int c=0;c<2;c++)
      #pragma unroll
      for (int r=0;r<4;r++){
        float p = __expf(pv[c][r]-mrow[r]);
        pv[c][r] = p; ts[r] += p;
      }
    #pragma unroll
    for (int m=1;m<16;m<<=1){
      #pragma unroll
      for (int r=0;r<4;r++) ts[r] += __shfl_xor(ts[r], m);
    }
    #pragma unroll
    for (int r=0;r<4;r++) lsum[r] = lsum[r]*al[r] + ts[r];
    #pragma unroll
    for (int co=0;co<4;co++)
      #pragma unroll
      for (int r=0;r<4;r++) o[co][r] *= al[r];
    // P -> bf16 -> LDS (wave-private), then PV via MFMA
    #pragma unroll
    for (int c=0;c<2;c++)
      #pragma unroll
      for (int r=0;r<4;r++)
        pl[wid][(lane>>4)*4 + r][c*16 + lrow] = f2bf(pv[c][r]);
    asm volatile("s_waitcnt lgkmcnt(0)" ::: "memory");
    short8 pf = *(const short8*)(&pl[wid][lrow][lk8]);
    #pragma unroll
    for (int co=0; co<4; co++){
      short8 vf = *(const short8*)(&vt[co*16 + lrow][lk8]);
      o[co] = __builtin_amdgcn_mfma_f32_16x16x32_bf16(pf, vf, o[co], 0,0,0);
    }
    __syncthreads();
  }
  const int b = bh / HH, h = bh % HH;
  #pragma unroll
  for (int r=0;r<4;r++){
    const float rl = 1.0f / lsum[r];
    const int qq = qw + (lane>>4)*4 + r;
    #pragma unroll
    for (int co=0;co<4;co++){
      rep[ ((size_t)(b*SS + qq)<<10) + h*64 + co*16 + lrow ] = f2bf(o[co][r]*rl);
    }
  }
}

// ---------------------------------------------------------------------------
extern "C" void kernel_launch(void* const* d_in, const int* in_sizes, int n_in,
                              void* d_out, int out_size, void* d_ws, size_t ws_size,
                              hipStream_t stream) {
  const float* decoder = (const float*)d_in[0];
  const float* encoder = (const float*)d_in[1];
  const float* sa_wq = (const float*)d_in[2];  const float* sa_bq = (const float*)d_in[3];
  const float* sa_wk = (const float*)d_in[4];  const float* sa_bk = (const float*)d_in[5];
  const float* sa_wv = (const float*)d_in[6];  const float* sa_bv = (const float*)d_in[7];
  const float* sa_wo = (const float*)d_in[8];  const float* sa_bo = (const float*)d_in[9];
  const float* ca_wq = (const float*)d_in[10]; const float* ca_bq = (const float*)d_in[11];
  const float* ca_wk = (const float*)d_in[12]; const float* ca_bk = (const float*)d_in[13];
  const float* ca_wv = (const float*)d_in[14]; const float* ca_bv = (const float*)d_in[15];
  const float* ca_wo = (const float*)d_in[16]; const float* ca_bo = (const float*)d_in[17];
  const float* ln1_g = (const float*)d_in[18]; const float* ln1_b = (const float*)d_in[19];
  const float* ln2_g = (const float*)d_in[20]; const float* ln2_b = (const float*)d_in[21];
  const float* ln3_g = (const float*)d_in[22]; const float* ln3_b = (const float*)d_in[23];
  const float* ffn_w1 = (const float*)d_in[24]; const float* ffn_b1 = (const float*)d_in[25];
  const float* ffn_w2 = (const float*)d_in[26]; const float* ffn_b2 = (const float*)d_in[27];

  char* ws = (char*)d_ws;
  const size_t MB = 1u<<20;
  u16* wt_saq = (u16*)(ws + 0*MB);
  u16* wt_sak = (u16*)(ws + 2*MB);
  u16* wt_sav = (u16*)(ws + 4*MB);
  u16* wt_sao = (u16*)(ws + 6*MB);
  u16* wt_caq = (u16*)(ws + 8*MB);
  u16* wt_cak = (u16*)(ws + 10*MB);
  u16* wt_cav = (u16*)(ws + 12*MB);
  u16* wt_cao = (u16*)(ws + 14*MB);
  u16* wt_w1  = (u16*)(ws + 16*MB);
  u16* wt_w2  = (u16*)(ws + 24*MB);
  u16* enc_bf = (u16*)(ws + 32*MB);
  u16* lnbuf  = (u16*)(ws + 48*MB);  // xln -> yln -> zln
  u16* qbuf   = (u16*)(ws + 64*MB);
  u16* kbuf   = (u16*)(ws + 80*MB);
  u16* vbuf   = (u16*)(ws + 96*MB);
  u16* repbuf = (u16*)(ws + 112*MB);
  u16* x2buf  = (u16*)(ws + 128*MB); // x2 -> y2
  u16* hbuf   = (u16*)(ws + 144*MB); // [8192,4096]

  const dim3 blk(256);
  // --- weight transposed casts ---
  wtrans_k<<<dim3(16,16), blk, 0, stream>>>(sa_wq, wt_saq, DD, DD);
  wtrans_k<<<dim3(16,16), blk, 0, stream>>>(sa_wk, wt_sak, DD, DD);
  wtrans_k<<<dim3(16,16), blk, 0, stream>>>(sa_wv, wt_sav, DD, DD);
  wtrans_k<<<dim3(16,16), blk, 0, stream>>>(sa_wo, wt_sao, DD, DD);
  wtrans_k<<<dim3(16,16), blk, 0, stream>>>(ca_wq, wt_caq, DD, DD);
  wtrans_k<<<dim3(16,16), blk, 0, stream>>>(ca_wk, wt_cak, DD, DD);
  wtrans_k<<<dim3(16,16), blk, 0, stream>>>(ca_wv, wt_cav, DD, DD);
  wtrans_k<<<dim3(16,16), blk, 0, stream>>>(ca_wo, wt_cao, DD, DD);
  wtrans_k<<<dim3(64,16), blk, 0, stream>>>(ffn_w1, wt_w1, DD, FFDIM);
  wtrans_k<<<dim3(16,64), blk, 0, stream>>>(ffn_w2, wt_w2, FFDIM, DD);
  // --- encoder cast ---
  cast_k<<<dim3(2048), blk, 0, stream>>>(encoder, enc_bf);
  // --- LN1 ---
  ln_k<0><<<dim3(MM), blk, 0, stream>>>(decoder, ln1_g, ln1_b, lnbuf);
  // --- self-attn QKV ---
  gemm_k<0><<<dim3(8,64), blk, 0, stream>>>(lnbuf, wt_saq, sa_bq, nullptr, qbuf, DD, DD);
  gemm_k<0><<<dim3(8,64), blk, 0, stream>>>(lnbuf, wt_sak, sa_bk, nullptr, kbuf, DD, DD);
  gemm_k<0><<<dim3(8,64), blk, 0, stream>>>(lnbuf, wt_sav, sa_bv, nullptr, vbuf, DD, DD);
  attn_k<1><<<dim3(2048), blk, 0, stream>>>(qbuf, kbuf, vbuf, repbuf);
  gemm_k<1><<<dim3(8,64), blk, 0, stream>>>(repbuf, wt_sao, sa_bo, lnbuf, x2buf, DD, DD);
  // --- LN2 ---
  ln_k<1><<<dim3(MM), blk, 0, stream>>>(x2buf, ln2_g, ln2_b, lnbuf);
  // --- cross-attn ---
  gemm_k<0><<<dim3(8,64), blk, 0, stream>>>(lnbuf,  wt_caq, ca_bq, nullptr, qbuf, DD, DD);
  gemm_k<0><<<dim3(8,64), blk, 0, stream>>>(enc_bf, wt_cak, ca_bk, nullptr, kbuf, DD, DD);
  gemm_k<0><<<dim3(8,64), blk, 0, stream>>>(enc_bf, wt_cav, ca_bv, nullptr, vbuf, DD, DD);
  attn_k<0><<<dim3(2048), blk, 0, stream>>>(qbuf, kbuf, vbuf, repbuf);
  gemm_k<1><<<dim3(8,64), blk, 0, stream>>>(repbuf, wt_cao, ca_bo, lnbuf, x2buf, DD, DD);
  // --- LN3 ---
  ln_k<1><<<dim3(MM), blk, 0, stream>>>(x2buf, ln3_g, ln3_b, lnbuf);
  // --- FFN ---
  gemm_k<2><<<dim3(32,64), blk, 0, stream>>>(lnbuf, wt_w1, ffn_b1, nullptr, hbuf, FFDIM, DD);
  gemm_k<3><<<dim3(8,64), blk, 0, stream>>>(hbuf, wt_w2, ffn_b2, lnbuf, d_out, DD, FFDIM);
}

// Round 2
// 883.560 us; speedup vs baseline: 1.2961x; 1.2961x over previous
//
#include <hip/hip_runtime.h>
#include <math.h>

typedef unsigned short u16;
typedef unsigned int u32;

typedef __attribute__((ext_vector_type(8))) short short8;
typedef __attribute__((ext_vector_type(4))) float floatx4;
typedef __attribute__((ext_vector_type(4))) unsigned short ushort4v;

#define DD 1024
#define HH 16
#define HD 64
#define SS 1024
#define BBATCH 8
#define FFDIM 4096
#define MM (BBATCH*SS)   // 8192 rows

__device__ __forceinline__ float bf2f(u16 v){ u32 x = ((u32)v)<<16; return __builtin_bit_cast(float, x); }
__device__ __forceinline__ u16 f2bf(float f){
  u32 x = __builtin_bit_cast(u32, f);
  u32 r = (x + 0x7fffu + ((x>>16)&1u)) >> 16;
  return (u16)r;
}

__device__ __forceinline__ void gload_lds16(const void* g, void* l){
  __builtin_amdgcn_global_load_lds((const __attribute__((address_space(1))) void*)g,
                                   (__attribute__((address_space(3))) void*)l, 16, 0, 0);
}

// ---------------------------------------------------------------------------
// Weight transpose + fp32->bf16 cast: W[K][N] -> Wt[N][K]
// ---------------------------------------------------------------------------
__global__ __launch_bounds__(256) void wtrans_k(const float* __restrict__ W,
                                                u16* __restrict__ Wt, int K, int N)
{
  __shared__ u16 tile[64][68];
  const int nt = blockIdx.x*64, kt = blockIdx.y*64;
  const int t = threadIdx.x;
  const int kl = t>>4, nl4 = (t&15)*4;
  #pragma unroll
  for (int r=0;r<4;r++){
    float4 v = *(const float4*)(W + (size_t)(kt + r*16 + kl)*N + nt + nl4);
    ushort4v u; u.x=f2bf(v.x); u.y=f2bf(v.y); u.z=f2bf(v.z); u.w=f2bf(v.w);
    *(ushort4v*)(&tile[r*16+kl][nl4]) = u;
  }
  __syncthreads();
  #pragma unroll
  for (int r=0;r<16;r++){
    int idx = r*256 + t;
    int nl = idx>>6, klc = idx&63;
    Wt[(size_t)(nt+nl)*K + kt + klc] = tile[klc][nl];
  }
}

// ---------------------------------------------------------------------------
// fp32 -> bf16 cast (8M elements)
// ---------------------------------------------------------------------------
__global__ __launch_bounds__(256) void cast_k(const float* __restrict__ in, u16* __restrict__ out)
{
  size_t i = (size_t)blockIdx.x*256 + threadIdx.x;
  #pragma unroll
  for (int r=0;r<4;r++){
    size_t idx = i + (size_t)r*524288;
    float4 v = ((const float4*)in)[idx];
    ushort4v u; u.x=f2bf(v.x); u.y=f2bf(v.y); u.z=f2bf(v.z); u.w=f2bf(v.w);
    ((ushort4v*)out)[idx] = u;
  }
}

// ---------------------------------------------------------------------------
// LayerNorm: one block (256 threads) per row of 1024.
// ---------------------------------------------------------------------------
template<int IN_BF16>
__global__ __launch_bounds__(256) void ln_k(const void* __restrict__ inv,
    const float* __restrict__ g, const float* __restrict__ bb, u16* __restrict__ out)
{
  const int row = blockIdx.x, t = threadIdx.x;
  float x[4];
  if (IN_BF16){
    const u16* in = (const u16*)inv;
    ushort4v v = ((const ushort4v*)(in + (size_t)row*DD))[t];
    #pragma unroll
    for (int i=0;i<4;i++) x[i]=bf2f(v[i]);
  } else {
    const float* in = (const float*)inv;
    float4 v = ((const float4*)(in + (size_t)row*DD))[t];
    x[0]=v.x; x[1]=v.y; x[2]=v.z; x[3]=v.w;
  }
  float s = x[0]+x[1]+x[2]+x[3];
  float q = x[0]*x[0]+x[1]*x[1]+x[2]*x[2]+x[3]*x[3];
  #pragma unroll
  for (int m=32;m;m>>=1){ s += __shfl_down(s,m); q += __shfl_down(q,m); }
  __shared__ float red[8];
  const int lane=t&63, wid=t>>6;
  if (lane==0){ red[wid]=s; red[wid+4]=q; }
  __syncthreads();
  s = red[0]+red[1]+red[2]+red[3];
  q = red[4]+red[5]+red[6]+red[7];
  const float mu = s*(1.0f/1024.0f);
  const float var = q*(1.0f/1024.0f) - mu*mu;
  const float rs = rsqrtf(var + 1e-5f);
  const int c = t*4;
  ushort4v ov;
  #pragma unroll
  for (int i=0;i<4;i++){
    float y = (x[i]-mu)*rs*g[c+i] + bb[c+i];
    ov[i] = f2bf(y);
  }
  ((ushort4v*)(out + (size_t)row*DD))[t] = ov;
}

// ---------------------------------------------------------------------------
// bf16 GEMM: C[M,N] = A[M,K] @ Wt[N,K]^T + bias.  128x128 tile, BK=32, 4 waves.
// XCD-aware bijective block swizzle (nwg % 8 == 0 for all our grids).
// ---------------------------------------------------------------------------
template<int MODE>
__global__ __launch_bounds__(256) void gemm_k(
    const u16* __restrict__ A, const u16* __restrict__ Bt,
    const float* __restrict__ bias, const u16* __restrict__ res,
    void* __restrict__ Cout, int N, int K)
{
  __shared__ u16 smem[8192];
  u16* sA = smem; u16* sB = smem + 4096;
  const int t = threadIdx.x;
  const int gx = gridDim.x;
  int bid = blockIdx.y * gx + blockIdx.x;
  const int nwg = gx * gridDim.y;
  bid = (bid & 7) * (nwg >> 3) + (bid >> 3);
  const int n0 = (bid % gx) * 128, m0 = (bid / gx) * 128;
  const int lane = t & 63, wid = t >> 6;
  const int wr = wid >> 1, wc = wid & 1;
  const int lrow = lane & 15, lk8 = (lane >> 4) * 8;

  floatx4 acc[4][4];
  #pragma unroll
  for (int i=0;i<4;i++)
    #pragma unroll
    for (int j=0;j<4;j++) acc[i][j] = (floatx4)0.0f;

  const u16* gA = A + (size_t)m0 * K;
  const u16* gB = Bt + (size_t)n0 * K;
  const int c0row = t >> 2, c0col = (t & 3) * 8;
  const int nk = K >> 5;
  for (int kt = 0; kt < nk; ++kt) {
    const u16* gAk = gA + kt*32;
    const u16* gBk = gB + kt*32;
    gload_lds16(gAk + (size_t)c0row * K + c0col,      sA + t*8);
    gload_lds16(gAk + (size_t)(c0row+64) * K + c0col, sA + 2048 + t*8);
    gload_lds16(gBk + (size_t)c0row * K + c0col,      sB + t*8);
    gload_lds16(gBk + (size_t)(c0row+64) * K + c0col, sB + 2048 + t*8);
    __syncthreads();
    short8 a[4], b[4];
    #pragma unroll
    for (int mi=0; mi<4; mi++) a[mi] = *(const short8*)(sA + (wr*64 + mi*16 + lrow)*32 + lk8);
    #pragma unroll
    for (int ni=0; ni<4; ni++) b[ni] = *(const short8*)(sB + (wc*64 + ni*16 + lrow)*32 + lk8);
    #pragma unroll
    for (int mi=0; mi<4; mi++)
      #pragma unroll
      for (int ni=0; ni<4; ni++)
        acc[mi][ni] = __builtin_amdgcn_mfma_f32_16x16x32_bf16(a[mi], b[ni], acc[mi][ni], 0,0,0);
    __syncthreads();
  }

  #pragma unroll
  for (int mi=0; mi<4; mi++) {
    const int row_base = m0 + wr*64 + mi*16 + (lane>>4)*4;
    #pragma unroll
    for (int ni=0; ni<4; ni++) {
      const int col = n0 + wc*64 + ni*16 + lrow;
      const float bv = bias[col];
      floatx4 v = acc[mi][ni];
      #pragma unroll
      for (int r=0;r<4;r++){
        const int row = row_base + r;
        float x = v[r] + bv;
        const size_t f = (size_t)row * N + col;
        if (MODE==0){
          const int b = row >> 10, s = row & 1023;
          const int h = col >> 6, d = col & 63;
          ((u16*)Cout)[ (((size_t)(b*HH+h)*SS + s)<<6) + d ] = f2bf(x);
        } else if (MODE==1){
          ((u16*)Cout)[f] = f2bf(x + bf2f(res[f]));
        } else if (MODE==2){
          float gx2 = 0.5f * x * (1.0f + erff(x * 0.70710678f));
          ((u16*)Cout)[f] = f2bf(gx2);
        } else {
          ((float*)Cout)[f] = x + bf2f(res[f]);
        }
      }
    }
  }
}

// ---------------------------------------------------------------------------
// Flash attention v2: swapped-QK 16x16 MFMA, KVBLK=64, 4 waves x 16 q-rows.
// S^T = mfma(K,Q): lane owns q=lane&15, keys (lane>>4)*4+r per 16-key tile.
// Softmax: 15 lane-local fmax + 2 shfl_xor. O accumulated transposed.
// K: [64][72] (conflict-free b128). V,P: flat XOR-swizzled (2-way stores).
// ---------------------------------------------------------------------------
template<int CAUSAL>
__global__ __launch_bounds__(256) void attn_k(
  const u16* __restrict__ Q, const u16* __restrict__ Kk, const u16* __restrict__ V,
  u16* __restrict__ rep)
{
  __shared__ u16 klds[64][72];
  __shared__ u16 vtf[4096];
  __shared__ u16 plds[4096];
  const int t = threadIdx.x, lane = t&63, wid = t>>6;
  int bidx = blockIdx.x;
  if (!CAUSAL) bidx = (bidx & 7) * 256 + (bidx >> 3);   // XCD swizzle (2048 % 8 == 0)
  const int qb = bidx & 15;
  const int bh = bidx >> 4;
  const int q0 = qb*64;
  const int qw = q0 + wid*16;
  const int lrow = lane&15, hi = lane>>4, lk8 = hi*8;
  const int q8 = lrow & 7;
  const int qrow = qw + lrow;
  const size_t base = (size_t)bh * SS * HD;

  short8 qf[2];
  {
    const u16* qp = Q + base + (size_t)(qw + lrow)*HD + lk8;
    qf[0] = *(const short8*)(qp);
    qf[1] = *(const short8*)(qp + 32);
  }
  floatx4 o[4];
  #pragma unroll
  for (int co=0;co<4;co++) o[co] = (floatx4)0.0f;
  float mrow = -INFINITY, lsum = 0.f;

  const int ntiles = CAUSAL ? (qb + 1) : (SS >> 6);
  for (int kt=0; kt<ntiles; ++kt){
    const int k0 = kt<<6;
    // ---- stage K/V tile: global -> regs (issued early) ----
    short8 kreg[2], vreg[2];
    #pragma unroll
    for (int rr=0; rr<2; ++rr){
      const int idx = rr*256 + t;
      const int row = idx>>3, c8 = (idx&7)*8;
      kreg[rr] = *(const short8*)(Kk + base + (size_t)(k0+row)*HD + c8);
      vreg[rr] = *(const short8*)(V  + base + (size_t)(k0+row)*HD + c8);
    }
    __syncthreads();   // prior tile's LDS reads done
    #pragma unroll
    for (int rr=0; rr<2; ++rr){
      const int idx = rr*256 + t;
      const int row = idx>>3, c8 = (idx&7)*8;
      *(short8*)(&klds[row][c8]) = kreg[rr];
      #pragma unroll
      for (int j=0;j<8;j++){
        const int d = c8+j;
        vtf[d*64 + ((((row>>3) ^ (d&7) ^ (d>>3))&7)<<3) + (row&7)] = (u16)vreg[rr][j];
      }
    }
    __syncthreads();

    // ---- S^T = K @ Q^T : 4 co tiles of 16 keys ----
    float pr[4][4];
    #pragma unroll
    for (int co=0;co<4;co++){
      short8 kf0 = *(const short8*)(&klds[co*16+lrow][lk8]);
      short8 kf1 = *(const short8*)(&klds[co*16+lrow][32+lk8]);
      floatx4 z = (floatx4)0.0f;
      z = __builtin_amdgcn_mfma_f32_16x16x32_bf16(kf0, qf[0], z, 0,0,0);
      z = __builtin_amdgcn_mfma_f32_16x16x32_bf16(kf1, qf[1], z, 0,0,0);
      #pragma unroll
      for (int r=0;r<4;r++){
        float s = z[r]*0.125f;
        if (CAUSAL){
          const int key = k0 + co*16 + hi*4 + r;
          if (key > qrow) s = -INFINITY;
        }
        pr[co][r] = s;
      }
    }
    // ---- online softmax: lane-local 16-value reduce + 2 shfls ----
    float tm = pr[0][0];
    #pragma unroll
    for (int co=0;co<4;co++)
      #pragma unroll
      for (int r=0;r<4;r++) tm = fmaxf(tm, pr[co][r]);
    tm = fmaxf(tm, __shfl_xor(tm, 16));
    tm = fmaxf(tm, __shfl_xor(tm, 32));
    const float mn = fmaxf(mrow, tm);
    const float al = __expf(mrow - mn);
    float ts = 0.f;
    #pragma unroll
    for (int co=0;co<4;co++)
      #pragma unroll
      for (int r=0;r<4;r++){
        const float p = __expf(pr[co][r]-mn);
        ts += p;
        const int klo = hi*4 + r;       // key = co*16 + klo
        plds[wid*1024 + lrow*64 + ((((co*2 + (hi>>1)) ^ q8)&7)<<3) + (klo&7)] = f2bf(p);
      }
    ts += __shfl_xor(ts, 16);
    ts += __shfl_xor(ts, 32);
    lsum = lsum*al + ts;
    mrow = mn;
    #pragma unroll
    for (int co=0;co<4;co++) o[co] *= al;

    asm volatile("s_waitcnt lgkmcnt(0)" ::: "memory");
    __builtin_amdgcn_sched_barrier(0);
    // ---- O^T += V^T @ P^T ----
    short8 pf0 = *(const short8*)(plds + wid*1024 + lrow*64 + (((hi   ^ q8)&7)<<3));
    short8 pf1 = *(const short8*)(plds + wid*1024 + lrow*64 + ((((hi+4)^ q8)&7)<<3));
    #pragma unroll
    for (int co=0; co<4; co++){
      const int d = co*16 + lrow;
      const int sx = (d&7) ^ (d>>3);
      short8 vf0 = *(const short8*)(vtf + d*64 + (((hi   ^ sx)&7)<<3));
      short8 vf1 = *(const short8*)(vtf + d*64 + ((((hi+4)^ sx)&7)<<3));
      o[co] = __builtin_amdgcn_mfma_f32_16x16x32_bf16(vf0, pf0, o[co], 0,0,0);
      o[co] = __builtin_amdgcn_mfma_f32_16x16x32_bf16(vf1, pf1, o[co], 0,0,0);
    }
    __syncthreads();
  }

  // ---- epilogue: O^T -> LDS (wave-private) -> coalesced global write ----
  const float rl = 1.0f / lsum;
  #pragma unroll
  for (int co=0;co<4;co++)
    #pragma unroll
    for (int r=0;r<4;r++){
      const int d = co*16 + hi*4 + r;
      plds[wid*1024 + lrow*64 + ((((d>>3) ^ q8)&7)<<3) + (d&7)] = f2bf(o[co][r]*rl);
    }
  asm volatile("s_waitcnt lgkmcnt(0)" ::: "memory");
  __builtin_amdgcn_sched_barrier(0);
  const int b = bh >> 4, h = bh & 15;
  #pragma unroll
  for (int it=0; it<2; ++it){
    const int idx = it*64 + lane;
    const int q = idx>>3, ch = idx&7;
    short8 vv = *(const short8*)(plds + wid*1024 + q*64 + (((ch ^ (q&7))&7)<<3));
    *(short8*)(rep + (((size_t)(b*SS + qw + q))<<10) + h*64 + ch*8) = vv;
  }
}

// ---------------------------------------------------------------------------
extern "C" void kernel_launch(void* const* d_in, const int* in_sizes, int n_in,
                              void* d_out, int out_size, void* d_ws, size_t ws_size,
                              hipStream_t stream) {
  const float* decoder = (const float*)d_in[0];
  const float* encoder = (const float*)d_in[1];
  const float* sa_wq = (const float*)d_in[2];  const float* sa_bq = (const float*)d_in[3];
  const float* sa_wk = (const float*)d_in[4];  const float* sa_bk = (const float*)d_in[5];
  const float* sa_wv = (const float*)d_in[6];  const float* sa_bv = (const float*)d_in[7];
  const float* sa_wo = (const float*)d_in[8];  const float* sa_bo = (const float*)d_in[9];
  const float* ca_wq = (const float*)d_in[10]; const float* ca_bq = (const float*)d_in[11];
  const float* ca_wk = (const float*)d_in[12]; const float* ca_bk = (const float*)d_in[13];
  const float* ca_wv = (const float*)d_in[14]; const float* ca_bv = (const float*)d_in[15];
  const float* ca_wo = (const float*)d_in[16]; const float* ca_bo = (const float*)d_in[17];
  const float* ln1_g = (const float*)d_in[18]; const float* ln1_b = (const float*)d_in[19];
  const float* ln2_g = (const float*)d_in[20]; const float* ln2_b = (const float*)d_in[21];
  const float* ln3_g = (const float*)d_in[22]; const float* ln3_b = (const float*)d_in[23];
  const float* ffn_w1 = (const float*)d_in[24]; const float* ffn_b1 = (const float*)d_in[25];
  const float* ffn_w2 = (const float*)d_in[26]; const float* ffn_b2 = (const float*)d_in[27];

  char* ws = (char*)d_ws;
  const size_t MB = 1u<<20;
  u16* wt_saq = (u16*)(ws + 0*MB);
  u16* wt_sak = (u16*)(ws + 2*MB);
  u16* wt_sav = (u16*)(ws + 4*MB);
  u16* wt_sao = (u16*)(ws + 6*MB);
  u16* wt_caq = (u16*)(ws + 8*MB);
  u16* wt_cak = (u16*)(ws + 10*MB);
  u16* wt_cav = (u16*)(ws + 12*MB);
  u16* wt_cao = (u16*)(ws + 14*MB);
  u16* wt_w1  = (u16*)(ws + 16*MB);
  u16* wt_w2  = (u16*)(ws + 24*MB);
  u16* enc_bf = (u16*)(ws + 32*MB);
  u16* lnbuf  = (u16*)(ws + 48*MB);
  u16* qbuf   = (u16*)(ws + 64*MB);
  u16* kbuf   = (u16*)(ws + 80*MB);
  u16* vbuf   = (u16*)(ws + 96*MB);
  u16* repbuf = (u16*)(ws + 112*MB);
  u16* x2buf  = (u16*)(ws + 128*MB);
  u16* hbuf   = (u16*)(ws + 144*MB);

  const dim3 blk(256);
  wtrans_k<<<dim3(16,16), blk, 0, stream>>>(sa_wq, wt_saq, DD, DD);
  wtrans_k<<<dim3(16,16), blk, 0, stream>>>(sa_wk, wt_sak, DD, DD);
  wtrans_k<<<dim3(16,16), blk, 0, stream>>>(sa_wv, wt_sav, DD, DD);
  wtrans_k<<<dim3(16,16), blk, 0, stream>>>(sa_wo, wt_sao, DD, DD);
  wtrans_k<<<dim3(16,16), blk, 0, stream>>>(ca_wq, wt_caq, DD, DD);
  wtrans_k<<<dim3(16,16), blk, 0, stream>>>(ca_wk, wt_cak, DD, DD);
  wtrans_k<<<dim3(16,16), blk, 0, stream>>>(ca_wv, wt_cav, DD, DD);
  wtrans_k<<<dim3(16,16), blk, 0, stream>>>(ca_wo, wt_cao, DD, DD);
  wtrans_k<<<dim3(64,16), blk, 0, stream>>>(ffn_w1, wt_w1, DD, FFDIM);
  wtrans_k<<<dim3(16,64), blk, 0, stream>>>(ffn_w2, wt_w2, FFDIM, DD);
  cast_k<<<dim3(2048), blk, 0, stream>>>(encoder, enc_bf);
  ln_k<0><<<dim3(MM), blk, 0, stream>>>(decoder, ln1_g, ln1_b, lnbuf);
  gemm_k<0><<<dim3(8,64), blk, 0, stream>>>(lnbuf, wt_saq, sa_bq, nullptr, qbuf, DD, DD);
  gemm_k<0><<<dim3(8,64), blk, 0, stream>>>(lnbuf, wt_sak, sa_bk, nullptr, kbuf, DD, DD);
  gemm_k<0><<<dim3(8,64), blk, 0, stream>>>(lnbuf, wt_sav, sa_bv, nullptr, vbuf, DD, DD);
  attn_k<1><<<dim3(2048), blk, 0, stream>>>(qbuf, kbuf, vbuf, repbuf);
  gemm_k<1><<<dim3(8,64), blk, 0, stream>>>(repbuf, wt_sao, sa_bo, lnbuf, x2buf, DD, DD);
  ln_k<1><<<dim3(MM), blk, 0, stream>>>(x2buf, ln2_g, ln2_b, lnbuf);
  gemm_k<0><<<dim3(8,64), blk, 0, stream>>>(lnbuf,  wt_caq, ca_bq, nullptr, qbuf, DD, DD);
  gemm_k<0><<<dim3(8,64), blk, 0, stream>>>(enc_bf, wt_cak, ca_bk, nullptr, kbuf, DD, DD);
  gemm_k<0><<<dim3(8,64), blk, 0, stream>>>(enc_bf, wt_cav, ca_bv, nullptr, vbuf, DD, DD);
  attn_k<0><<<dim3(2048), blk, 0, stream>>>(qbuf, kbuf, vbuf, repbuf);
  gemm_k<1><<<dim3(8,64), blk, 0, stream>>>(repbuf, wt_cao, ca_bo, lnbuf, x2buf, DD, DD);
  ln_k<1><<<dim3(MM), blk, 0, stream>>>(x2buf, ln3_g, ln3_b, lnbuf);
  gemm_k<2><<<dim3(32,64), blk, 0, stream>>>(lnbuf, wt_w1, ffn_b1, nullptr, hbuf, FFDIM, DD);
  gemm_k<3><<<dim3(8,64), blk, 0, stream>>>(hbuf, wt_w2, ffn_b2, lnbuf, d_out, DD, FFDIM);
}

// Round 7
// 804.090 us; speedup vs baseline: 1.4242x; 1.0988x over previous
//
#include <hip/hip_runtime.h>
#include <math.h>

typedef unsigned short u16;
typedef unsigned int u32;

typedef __attribute__((ext_vector_type(8))) short short8;
typedef __attribute__((ext_vector_type(4))) float floatx4;
typedef __attribute__((ext_vector_type(4))) unsigned short ushort4v;

#define DD 1024
#define HH 16
#define HD 64
#define SS 1024
#define BBATCH 8
#define FFDIM 4096
#define MM (BBATCH*SS)   // 8192 rows

__device__ __forceinline__ float bf2f(u16 v){ u32 x = ((u32)v)<<16; return __builtin_bit_cast(float, x); }
__device__ __forceinline__ u16 f2bf(float f){
  u32 x = __builtin_bit_cast(u32, f);
  u32 r = (x + 0x7fffu + ((x>>16)&1u)) >> 16;
  return (u16)r;
}

__device__ __forceinline__ void gload_lds16(const void* g, void* l){
  __builtin_amdgcn_global_load_lds((const __attribute__((address_space(1))) void*)g,
                                   (__attribute__((address_space(3))) void*)l, 16, 0, 0);
}

// ---------------------------------------------------------------------------
// Weight transpose + fp32->bf16 cast: W[K][N] -> Wt[N][K]
// ---------------------------------------------------------------------------
__global__ __launch_bounds__(256) void wtrans_k(const float* __restrict__ W,
                                                u16* __restrict__ Wt, int K, int N)
{
  __shared__ u16 tile[64][68];
  const int nt = blockIdx.x*64, kt = blockIdx.y*64;
  const int t = threadIdx.x;
  const int kl = t>>4, nl4 = (t&15)*4;
  #pragma unroll
  for (int r=0;r<4;r++){
    float4 v = *(const float4*)(W + (size_t)(kt + r*16 + kl)*N + nt + nl4);
    ushort4v u; u.x=f2bf(v.x); u.y=f2bf(v.y); u.z=f2bf(v.z); u.w=f2bf(v.w);
    *(ushort4v*)(&tile[r*16+kl][nl4]) = u;
  }
  __syncthreads();
  #pragma unroll
  for (int r=0;r<16;r++){
    int idx = r*256 + t;
    int nl = idx>>6, klc = idx&63;
    Wt[(size_t)(nt+nl)*K + kt + klc] = tile[klc][nl];
  }
}

// ---------------------------------------------------------------------------
// fp32 -> bf16 cast (8M elements)
// ---------------------------------------------------------------------------
__global__ __launch_bounds__(256) void cast_k(const float* __restrict__ in, u16* __restrict__ out)
{
  size_t i = (size_t)blockIdx.x*256 + threadIdx.x;
  #pragma unroll
  for (int r=0;r<4;r++){
    size_t idx = i + (size_t)r*524288;
    float4 v = ((const float4*)in)[idx];
    ushort4v u; u.x=f2bf(v.x); u.y=f2bf(v.y); u.z=f2bf(v.z); u.w=f2bf(v.w);
    ((ushort4v*)out)[idx] = u;
  }
}

// ---------------------------------------------------------------------------
// LayerNorm: one block (256 threads) per row of 1024.
// ---------------------------------------------------------------------------
template<int IN_BF16>
__global__ __launch_bounds__(256) void ln_k(const void* __restrict__ inv,
    const float* __restrict__ g, const float* __restrict__ bb, u16* __restrict__ out)
{
  const int row = blockIdx.x, t = threadIdx.x;
  float x[4];
  if (IN_BF16){
    const u16* in = (const u16*)inv;
    ushort4v v = ((const ushort4v*)(in + (size_t)row*DD))[t];
    #pragma unroll
    for (int i=0;i<4;i++) x[i]=bf2f(v[i]);
  } else {
    const float* in = (const float*)inv;
    float4 v = ((const float4*)(in + (size_t)row*DD))[t];
    x[0]=v.x; x[1]=v.y; x[2]=v.z; x[3]=v.w;
  }
  float s = x[0]+x[1]+x[2]+x[3];
  float q = x[0]*x[0]+x[1]*x[1]+x[2]*x[2]+x[3]*x[3];
  #pragma unroll
  for (int m=32;m;m>>=1){ s += __shfl_down(s,m); q += __shfl_down(q,m); }
  __shared__ float red[8];
  const int lane=t&63, wid=t>>6;
  if (lane==0){ red[wid]=s; red[wid+4]=q; }
  __syncthreads();
  s = red[0]+red[1]+red[2]+red[3];
  q = red[4]+red[5]+red[6]+red[7];
  const float mu = s*(1.0f/1024.0f);
  const float var = q*(1.0f/1024.0f) - mu*mu;
  const float rs = rsqrtf(var + 1e-5f);
  const int c = t*4;
  ushort4v ov;
  #pragma unroll
  for (int i=0;i<4;i++){
    float y = (x[i]-mu)*rs*g[c+i] + bb[c+i];
    ov[i] = f2bf(y);
  }
  ((ushort4v*)(out + (size_t)row*DD))[t] = ov;
}

// ---------------------------------------------------------------------------
// 256x256-tile 8-phase bf16 GEMM (m201 template, plain HIP).
// C[M,N] = A[M,K] @ Bt[N,K]^T (+bias, +res per MODE).
// 512 threads = 8 waves (2M x 4N); BK=64; LDS 128 KiB double-buffered;
// one half-tile staged per phase; counted vmcnt(4) at phases 4/8 only;
// XOR slot-swizzle (slot ^= row&7) via pre-swizzled global source.
// MODE 0: scatter to q/k/v [B,H,S,HD] by col>>10 (3-way bias select)
// MODE 1: bf16 flat + res     MODE 2: bf16 flat + exact GELU
// MODE 4: split-K=2 fp32 partials (grid 2x128, half = bid>>7)
// ---------------------------------------------------------------------------
#define FRAG_A(mi, ks) (*(const short8*)(At  + (wm*128 + (mi)*16 + lrow)*64 + ((((ks)*4+hi) ^ swz)*8)))
#define FRAG_B(ni, ks) (*(const short8*)(Btl + (wn*64  + (ni)*16 + lrow)*64 + ((((ks)*4+hi) ^ swz)*8)))

#define GPHASE(BUF, PP, STAGECALL, DOVM)                                      \
  { const u16* At  = &lds[(BUF)*32768];                                       \
    const u16* Btl = &lds[(BUF)*32768 + 16384];                               \
    if ((PP)==0){                                                             \
      _Pragma("unroll") for (int ni=0; ni<4; ni++){                           \
        bfr[ni][0] = FRAG_B(ni, 0);                                           \
        bfr[ni][1] = FRAG_B(ni, 1);                                           \
      }                                                                       \
    }                                                                         \
    short8 af0k0 = FRAG_A((PP)*2+0, 0), af0k1 = FRAG_A((PP)*2+0, 1);          \
    short8 af1k0 = FRAG_A((PP)*2+1, 0), af1k1 = FRAG_A((PP)*2+1, 1);          \
    STAGECALL;                                                                \
    if (DOVM) { asm volatile("s_waitcnt vmcnt(4)" ::: "memory"); }            \
    __builtin_amdgcn_s_barrier();                                             \
    __builtin_amdgcn_sched_barrier(0);                                        \
    __builtin_amdgcn_s_setprio(1);                                            \
    _Pragma("unroll") for (int ni=0; ni<4; ni++){                             \
      acc[(PP)*2+0][ni] = __builtin_amdgcn_mfma_f32_16x16x32_bf16(af0k0, bfr[ni][0], acc[(PP)*2+0][ni], 0,0,0); \
      acc[(PP)*2+0][ni] = __builtin_amdgcn_mfma_f32_16x16x32_bf16(af0k1, bfr[ni][1], acc[(PP)*2+0][ni], 0,0,0); \
      acc[(PP)*2+1][ni] = __builtin_amdgcn_mfma_f32_16x16x32_bf16(af1k0, bfr[ni][0], acc[(PP)*2+1][ni], 0,0,0); \
      acc[(PP)*2+1][ni] = __builtin_amdgcn_mfma_f32_16x16x32_bf16(af1k1, bfr[ni][1], acc[(PP)*2+1][ni], 0,0,0); \
    }                                                                         \
    __builtin_amdgcn_s_setprio(0);                                            \
    __builtin_amdgcn_sched_barrier(0);                                        \
    __builtin_amdgcn_s_barrier();                                             \
    __builtin_amdgcn_sched_barrier(0);                                        \
  }

template<int MODE>
__global__ __launch_bounds__(512, 2) void gemm8_k(
    const u16* __restrict__ A, const u16* __restrict__ Bt,
    const float* __restrict__ b0, const float* __restrict__ b1, const float* __restrict__ b2,
    const u16* __restrict__ res, void* __restrict__ Cout,
    int N, int K, int nk, int nbx)
{
  __shared__ __align__(16) u16 lds[65536];   // 128 KiB: buf0.A | buf0.B | buf1.A | buf1.B
  const int t = threadIdx.x;
  int bid = blockIdx.x;
  const int nwg = gridDim.x;
  bid = (bid & 7) * (nwg >> 3) + (bid >> 3);     // bijective XCD swizzle (nwg%8==0)
  int koff = 0; size_t outoff = 0;
  if (MODE==4){ const int half = bid >> 7; bid &= 127; koff = half*2048; outoff = (size_t)half*8388608; }
  const int n0 = (bid % nbx) * 256;
  const int m0 = (bid / nbx) * 256;
  const int lane = t & 63, wid = t >> 6;
  const int wm = wid >> 2, wn = wid & 3;
  const int lrow = lane & 15, hi = lane >> 4;
  const int swz = lrow & 7;

  floatx4 acc[8][4];
  #pragma unroll
  for (int i=0;i<8;i++)
    #pragma unroll
    for (int j=0;j<4;j++) acc[i][j] = (floatx4)0.0f;
  short8 bfr[4][2];

  const u16* gA0 = A  + (size_t)m0       * K + koff;
  const u16* gA1 = A  + (size_t)(m0+128) * K + koff;
  const u16* gB0 = Bt + (size_t)n0       * K + koff;
  const u16* gB1 = Bt + (size_t)(n0+128) * K + koff;

  // stage constants: thread t loads rows (t>>3) and (t>>3)+64 of a 128-row half;
  // global slot pre-swizzled so linear LDS dest holds slot^(row&7) (involution).
  const int sr = t >> 3;
  const int sg = ((t & 7) ^ (sr & 7)) * 8;
  auto stage = [&](const u16* gbase, int kt, int ldsoff){
    const u16* g = gbase + (size_t)sr*K + kt*64 + sg;
    gload_lds16(g,                 &lds[ldsoff + t*8]);
    gload_lds16(g + (size_t)64*K,  &lds[ldsoff + 4096 + t*8]);
  };

  // prologue: tile0.A, tile0.B, tile1.B  (12 issues); wait tile0 (oldest 8)
  stage(gA0, 0, 0);      stage(gA1, 0, 8192);
  stage(gB0, 0, 16384);  stage(gB1, 0, 24576);
  stage(gB0, 1, 49152);  stage(gB1, 1, 57344);
  asm volatile("s_waitcnt vmcnt(4)" ::: "memory");
  __builtin_amdgcn_s_barrier();
  __builtin_amdgcn_sched_barrier(0);

  const int mask = nk - 1;                 // nk is a power of two
  for (int j = 0; j < (nk >> 1); ++j){
    const int c0 = 2*j;
    const int k1 = c0 + 1;
    const int k2 = (c0 + 2) & mask;
    const int k3 = (c0 + 3) & mask;
    GPHASE(0, 0, stage(gA0, k1, 32768), 0)   // P1: stage (c+1).A.h0 -> buf1.A
    GPHASE(0, 1, stage(gA1, k1, 40960), 0)   // P2: (c+1).A.h1
    GPHASE(0, 2, stage(gB0, k2, 16384), 0)   // P3: (c+2).B.h0 -> buf0.B (freed @P1)
    GPHASE(0, 3, stage(gB1, k2, 24576), 1)   // P4: (c+2).B.h1; vmcnt(4)
    GPHASE(1, 0, stage(gA0, k2, 0),     0)   // P5: (c+2).A.h0 -> buf0.A (freed @P4)
    GPHASE(1, 1, stage(gA1, k2, 8192),  0)   // P6: (c+2).A.h1
    GPHASE(1, 2, stage(gB0, k3, 49152), 0)   // P7: (c+3).B.h0 -> buf1.B (freed @P5)
    GPHASE(1, 3, stage(gB1, k3, 57344), 1)   // P8: (c+3).B.h1; vmcnt(4)
  }
  asm volatile("s_waitcnt vmcnt(0)" ::: "memory");  // drain wrapped stages before exit

  // ---- epilogue ----
  #pragma unroll
  for (int mi=0; mi<8; mi++) {
    const int row_base = m0 + wm*128 + mi*16 + hi*4;
    #pragma unroll
    for (int ni=0; ni<4; ni++) {
      const int col = n0 + wn*64 + ni*16 + lrow;
      float bv = 0.f;
      if (MODE==0){ const float* bp = (col<1024)?b0:((col<2048)?b1:b2); bv = bp[col&1023]; }
      else if (MODE==1 || MODE==2) bv = b0[col];
      floatx4 v = acc[mi][ni];
      #pragma unroll
      for (int r=0;r<4;r++){
        const int row = row_base + r;
        float x = v[r] + bv;
        const size_t f = (size_t)row * N + col;
        if (MODE==0){
          const int bb = row >> 10, s = row & 1023;
          const int cc = col & 1023;
          const int h = cc >> 6, d = cc & 63;
          ((u16*)Cout)[ (size_t)(col>>10)*8388608 + (((size_t)(bb*HH+h)*SS + s)<<6) + d ] = f2bf(x);
        } else if (MODE==1){
          ((u16*)Cout)[f] = f2bf(x + bf2f(res[f]));
        } else if (MODE==2){
          float gx2 = 0.5f * x * (1.0f + erff(x * 0.70710678f));
          ((u16*)Cout)[f] = f2bf(gx2);
        } else {
          ((float*)Cout)[outoff + f] = x;
        }
      }
    }
  }
}

// ---------------------------------------------------------------------------
// split-K combine: out = p0 + p1 + bias + res   (fp32 out)
// ---------------------------------------------------------------------------
__global__ __launch_bounds__(256) void combine_k(
    const float* __restrict__ p0, const float* __restrict__ p1,
    const float* __restrict__ bias, const u16* __restrict__ res, float* __restrict__ out)
{
  const size_t i = (size_t)blockIdx.x*256 + threadIdx.x;  // float4 index
  float4 a = ((const float4*)p0)[i];
  float4 b = ((const float4*)p1)[i];
  const int col = ((int)(i & 255)) * 4;
  float4 bv = *(const float4*)(bias + col);
  ushort4v r = ((const ushort4v*)res)[i];
  float4 o;
  o.x = a.x + b.x + bv.x + bf2f(r.x);
  o.y = a.y + b.y + bv.y + bf2f(r.y);
  o.z = a.z + b.z + bv.z + bf2f(r.z);
  o.w = a.w + b.w + bv.w + bf2f(r.w);
  ((float4*)out)[i] = o;
}

// ---------------------------------------------------------------------------
// Flash attention (R2 version): swapped-QK 16x16 MFMA, KVBLK=64, 4 waves.
// ---------------------------------------------------------------------------
template<int CAUSAL>
__global__ __launch_bounds__(256) void attn_k(
  const u16* __restrict__ Q, const u16* __restrict__ Kk, const u16* __restrict__ V,
  u16* __restrict__ rep)
{
  __shared__ u16 klds[64][72];
  __shared__ u16 vtf[4096];
  __shared__ u16 plds[4096];
  const int t = threadIdx.x, lane = t&63, wid = t>>6;
  int bidx = blockIdx.x;
  if (!CAUSAL) bidx = (bidx & 7) * 256 + (bidx >> 3);
  const int qb = bidx & 15;
  const int bh = bidx >> 4;
  const int q0 = qb*64;
  const int qw = q0 + wid*16;
  const int lrow = lane&15, hi = lane>>4, lk8 = hi*8;
  const int q8 = lrow & 7;
  const int qrow = qw + lrow;
  const size_t base = (size_t)bh * SS * HD;

  short8 qf[2];
  {
    const u16* qp = Q + base + (size_t)(qw + lrow)*HD + lk8;
    qf[0] = *(const short8*)(qp);
    qf[1] = *(const short8*)(qp + 32);
  }
  floatx4 o[4];
  #pragma unroll
  for (int co=0;co<4;co++) o[co] = (floatx4)0.0f;
  float mrow = -INFINITY, lsum = 0.f;

  const int ntiles = CAUSAL ? (qb + 1) : (SS >> 6);
  for (int kt=0; kt<ntiles; ++kt){
    const int k0 = kt<<6;
    short8 kreg[2], vreg[2];
    #pragma unroll
    for (int rr=0; rr<2; ++rr){
      const int idx = rr*256 + t;
      const int row = idx>>3, c8 = (idx&7)*8;
      kreg[rr] = *(const short8*)(Kk + base + (size_t)(k0+row)*HD + c8);
      vreg[rr] = *(const short8*)(V  + base + (size_t)(k0+row)*HD + c8);
    }
    __syncthreads();
    #pragma unroll
    for (int rr=0; rr<2; ++rr){
      const int idx = rr*256 + t;
      const int row = idx>>3, c8 = (idx&7)*8;
      *(short8*)(&klds[row][c8]) = kreg[rr];
      #pragma unroll
      for (int j=0;j<8;j++){
        const int d = c8+j;
        vtf[d*64 + ((((row>>3) ^ (d&7) ^ (d>>3))&7)<<3) + (row&7)] = (u16)vreg[rr][j];
      }
    }
    __syncthreads();

    float pr[4][4];
    #pragma unroll
    for (int co=0;co<4;co++){
      short8 kf0 = *(const short8*)(&klds[co*16+lrow][lk8]);
      short8 kf1 = *(const short8*)(&klds[co*16+lrow][32+lk8]);
      floatx4 z = (floatx4)0.0f;
      z = __builtin_amdgcn_mfma_f32_16x16x32_bf16(kf0, qf[0], z, 0,0,0);
      z = __builtin_amdgcn_mfma_f32_16x16x32_bf16(kf1, qf[1], z, 0,0,0);
      #pragma unroll
      for (int r=0;r<4;r++){
        float s = z[r]*0.125f;
        if (CAUSAL){
          const int key = k0 + co*16 + hi*4 + r;
          if (key > qrow) s = -INFINITY;
        }
        pr[co][r] = s;
      }
    }
    float tm = pr[0][0];
    #pragma unroll
    for (int co=0;co<4;co++)
      #pragma unroll
      for (int r=0;r<4;r++) tm = fmaxf(tm, pr[co][r]);
    tm = fmaxf(tm, __shfl_xor(tm, 16));
    tm = fmaxf(tm, __shfl_xor(tm, 32));
    const float mn = fmaxf(mrow, tm);
    const float al = __expf(mrow - mn);
    float ts = 0.f;
    #pragma unroll
    for (int co=0;co<4;co++)
      #pragma unroll
      for (int r=0;r<4;r++){
        const float p = __expf(pr[co][r]-mn);
        ts += p;
        const int klo = hi*4 + r;
        plds[wid*1024 + lrow*64 + ((((co*2 + (hi>>1)) ^ q8)&7)<<3) + (klo&7)] = f2bf(p);
      }
    ts += __shfl_xor(ts, 16);
    ts += __shfl_xor(ts, 32);
    lsum = lsum*al + ts;
    mrow = mn;
    #pragma unroll
    for (int co=0;co<4;co++) o[co] *= al;

    asm volatile("s_waitcnt lgkmcnt(0)" ::: "memory");
    __builtin_amdgcn_sched_barrier(0);
    short8 pf0 = *(const short8*)(plds + wid*1024 + lrow*64 + (((hi   ^ q8)&7)<<3));
    short8 pf1 = *(const short8*)(plds + wid*1024 + lrow*64 + ((((hi+4)^ q8)&7)<<3));
    #pragma unroll
    for (int co=0; co<4; co++){
      const int d = co*16 + lrow;
      const int sx = (d&7) ^ (d>>3);
      short8 vf0 = *(const short8*)(vtf + d*64 + (((hi   ^ sx)&7)<<3));
      short8 vf1 = *(const short8*)(vtf + d*64 + ((((hi+4)^ sx)&7)<<3));
      o[co] = __builtin_amdgcn_mfma_f32_16x16x32_bf16(vf0, pf0, o[co], 0,0,0);
      o[co] = __builtin_amdgcn_mfma_f32_16x16x32_bf16(vf1, pf1, o[co], 0,0,0);
    }
    __syncthreads();
  }

  const float rl = 1.0f / lsum;
  #pragma unroll
  for (int co=0;co<4;co++)
    #pragma unroll
    for (int r=0;r<4;r++){
      const int d = co*16 + hi*4 + r;
      plds[wid*1024 + lrow*64 + ((((d>>3) ^ q8)&7)<<3) + (d&7)] = f2bf(o[co][r]*rl);
    }
  asm volatile("s_waitcnt lgkmcnt(0)" ::: "memory");
  __builtin_amdgcn_sched_barrier(0);
  const int b = bh >> 4, h = bh & 15;
  #pragma unroll
  for (int it=0; it<2; ++it){
    const int idx = it*64 + lane;
    const int q = idx>>3, ch = idx&7;
    short8 vv = *(const short8*)(plds + wid*1024 + q*64 + (((ch ^ (q&7))&7)<<3));
    *(short8*)(rep + (((size_t)(b*SS + qw + q))<<10) + h*64 + ch*8) = vv;
  }
}

// ---------------------------------------------------------------------------
extern "C" void kernel_launch(void* const* d_in, const int* in_sizes, int n_in,
                              void* d_out, int out_size, void* d_ws, size_t ws_size,
                              hipStream_t stream) {
  const float* decoder = (const float*)d_in[0];
  const float* encoder = (const float*)d_in[1];
  const float* sa_wq = (const float*)d_in[2];  const float* sa_bq = (const float*)d_in[3];
  const float* sa_wk = (const float*)d_in[4];  const float* sa_bk = (const float*)d_in[5];
  const float* sa_wv = (const float*)d_in[6];  const float* sa_bv = (const float*)d_in[7];
  const float* sa_wo = (const float*)d_in[8];  const float* sa_bo = (const float*)d_in[9];
  const float* ca_wq = (const float*)d_in[10]; const float* ca_bq = (const float*)d_in[11];
  const float* ca_wk = (const float*)d_in[12]; const float* ca_bk = (const float*)d_in[13];
  const float* ca_wv = (const float*)d_in[14]; const float* ca_bv = (const float*)d_in[15];
  const float* ca_wo = (const float*)d_in[16]; const float* ca_bo = (const float*)d_in[17];
  const float* ln1_g = (const float*)d_in[18]; const float* ln1_b = (const float*)d_in[19];
  const float* ln2_g = (const float*)d_in[20]; const float* ln2_b = (const float*)d_in[21];
  const float* ln3_g = (const float*)d_in[22]; const float* ln3_b = (const float*)d_in[23];
  const float* ffn_w1 = (const float*)d_in[24]; const float* ffn_b1 = (const float*)d_in[25];
  const float* ffn_w2 = (const float*)d_in[26]; const float* ffn_b2 = (const float*)d_in[27];

  char* ws = (char*)d_ws;
  const size_t MB = 1u<<20;
  u16* wt_saq = (u16*)(ws + 0*MB);     // [3072][1024] fused with sak, sav
  u16* wt_sak = (u16*)(ws + 2*MB);
  u16* wt_sav = (u16*)(ws + 4*MB);
  u16* wt_sao = (u16*)(ws + 6*MB);
  u16* wt_caq = (u16*)(ws + 8*MB);
  u16* wt_cak = (u16*)(ws + 10*MB);    // [2048][1024] fused with cav
  u16* wt_cav = (u16*)(ws + 12*MB);
  u16* wt_cao = (u16*)(ws + 14*MB);
  u16* wt_w1  = (u16*)(ws + 16*MB);
  u16* wt_w2  = (u16*)(ws + 24*MB);
  u16* enc_bf = (u16*)(ws + 32*MB);
  u16* lnbuf  = (u16*)(ws + 48*MB);
  u16* qbuf   = (u16*)(ws + 64*MB);
  u16* kbuf   = (u16*)(ws + 80*MB);
  u16* vbuf   = (u16*)(ws + 96*MB);
  u16* repbuf = (u16*)(ws + 112*MB);
  u16* x2buf  = (u16*)(ws + 128*MB);
  u16* hbuf   = (u16*)(ws + 144*MB);   // [8192][4096] bf16
  float* pbuf = (float*)(ws + 64*MB);  // split-K partials overlay q/k/v/rep (dead by FFN2)

  const dim3 blk(256);
  wtrans_k<<<dim3(16,16), blk, 0, stream>>>(sa_wq, wt_saq, DD, DD);
  wtrans_k<<<dim3(16,16), blk, 0, stream>>>(sa_wk, wt_sak, DD, DD);
  wtrans_k<<<dim3(16,16), blk, 0, stream>>>(sa_wv, wt_sav, DD, DD);
  wtrans_k<<<dim3(16,16), blk, 0, stream>>>(sa_wo, wt_sao, DD, DD);
  wtrans_k<<<dim3(16,16), blk, 0, stream>>>(ca_wq, wt_caq, DD, DD);
  wtrans_k<<<dim3(16,16), blk, 0, stream>>>(ca_wk, wt_cak, DD, DD);
  wtrans_k<<<dim3(16,16), blk, 0, stream>>>(ca_wv, wt_cav, DD, DD);
  wtrans_k<<<dim3(16,16), blk, 0, stream>>>(ca_wo, wt_cao, DD, DD);
  wtrans_k<<<dim3(64,16), blk, 0, stream>>>(ffn_w1, wt_w1, DD, FFDIM);
  wtrans_k<<<dim3(16,64), blk, 0, stream>>>(ffn_w2, wt_w2, FFDIM, DD);
  cast_k<<<dim3(2048), blk, 0, stream>>>(encoder, enc_bf);
  ln_k<0><<<dim3(MM), blk, 0, stream>>>(decoder, ln1_g, ln1_b, lnbuf);
  // self-attn: fused QKV (N=3072)
  gemm8_k<0><<<dim3(384), dim3(512), 0, stream>>>(lnbuf, wt_saq, sa_bq, sa_bk, sa_bv,
      nullptr, qbuf, 3072, 1024, 16, 12);
  attn_k<1><<<dim3(2048), blk, 0, stream>>>(qbuf, kbuf, vbuf, repbuf);
  gemm8_k<1><<<dim3(128), dim3(512), 0, stream>>>(repbuf, wt_sao, sa_bo, nullptr, nullptr,
      lnbuf, x2buf, 1024, 1024, 16, 4);
  ln_k<1><<<dim3(MM), blk, 0, stream>>>(x2buf, ln2_g, ln2_b, lnbuf);
  // cross-attn: Q from yln, fused KV from encoder (N=2048)
  gemm8_k<0><<<dim3(128), dim3(512), 0, stream>>>(lnbuf, wt_caq, ca_bq, nullptr, nullptr,
      nullptr, qbuf, 1024, 1024, 16, 4);
  gemm8_k<0><<<dim3(256), dim3(512), 0, stream>>>(enc_bf, wt_cak, ca_bk, ca_bv, nullptr,
      nullptr, kbuf, 2048, 1024, 16, 8);
  attn_k<0><<<dim3(2048), blk, 0, stream>>>(qbuf, kbuf, vbuf, repbuf);
  gemm8_k<1><<<dim3(128), dim3(512), 0, stream>>>(repbuf, wt_cao, ca_bo, nullptr, nullptr,
      lnbuf, x2buf, 1024, 1024, 16, 4);
  ln_k<1><<<dim3(MM), blk, 0, stream>>>(x2buf, ln3_g, ln3_b, lnbuf);
  // FFN
  gemm8_k<2><<<dim3(512), dim3(512), 0, stream>>>(lnbuf, wt_w1, ffn_b1, nullptr, nullptr,
      nullptr, hbuf, 4096, 1024, 16, 16);
  gemm8_k<4><<<dim3(256), dim3(512), 0, stream>>>(hbuf, wt_w2, nullptr, nullptr, nullptr,
      nullptr, pbuf, 1024, 4096, 32, 4);
  combine_k<<<dim3(8192), blk, 0, stream>>>(pbuf, pbuf + 8388608, ffn_b2, lnbuf, (float*)d_out);
}